// Round 7
// baseline (421.580 us; speedup 1.0000x reference)
//
#include <hip/hip_runtime.h>
#include <hip/hip_bf16.h>

// Problem constants (reference: n=8192, d=1024, T=0.2, eps=1e-8)
#define NN 8192
#define DD 1024
#define NTILE 64           // 8192/128 tile blocks per dim
#define NOD (64 * 63 / 2)  // 2016 strict-upper off-diag tiles
#define NUT (NOD + 64)     // + 64 diagonal tiles (scheduled last)

typedef __attribute__((ext_vector_type(4))) int i32x4;
typedef __attribute__((ext_vector_type(8))) int i32x8;       // 32B fp8 MFMA operand
typedef __attribute__((ext_vector_type(4))) float floatx4;   // MFMA C/D frag
typedef __attribute__((ext_vector_type(8))) _Float16 h16x8;  // 16B of fp16

__device__ __forceinline__ void load_lds16(const void* g, void* l) {
  // async global->LDS, 16B per lane; LDS dest = wave-uniform base + lane*16
  __builtin_amdgcn_global_load_lds(
      (const __attribute__((address_space(1))) unsigned int*)g,
      (__attribute__((address_space(3))) unsigned int*)l, 16, 0, 0);
}

// Block order: t < NOD -> strict-upper (bi<bj) row-major; t >= NOD -> diag.
// Diagonal tiles run last (lighter: no pass-2) to shrink the drain tail.
__device__ __forceinline__ void tile_decode(int t, int& bi, int& bj) {
  if (t >= NOD) { bi = bj = t - NOD; return; }
  // start(b) = (127*b - b*b)/2 ; row b has 63-b entries
  int b = (int)((127.0 - sqrt(127.0 * 127.0 - 8.0 * (double)t)) * 0.5);
  if (b < 0) b = 0;
  while ((127 * (b + 1) - (b + 1) * (b + 1)) / 2 <= t) ++b;
  while ((127 * b - b * b) / 2 > t) --b;
  bi = b;
  bj = b + 1 + (t - (127 * b - b * b) / 2);
}

// Kernel 1: row L2-normalize, scale by 16, cast to fp8 e4m3 (packed 4/thread).
// Scale 16 centers unit-norm components (~1/32) in e4m3's range; the GEMM
// result is then 256*sim, rescaled by 5/256 in the epilogue.
// Also zero-inits the 3 per-row accumulators.
__global__ __launch_bounds__(256) void normalize_kernel(
    const float* __restrict__ embs, unsigned int* __restrict__ xq,
    float* __restrict__ accL, float* __restrict__ accS1,
    float* __restrict__ accS2) {
  const int row = blockIdx.x;
  const int t = threadIdx.x;
  if (t == 0) { accL[row] = 0.f; accS1[row] = 0.f; accS2[row] = 0.f; }
  const float4 v = ((const float4*)(embs + (size_t)row * DD))[t];
  float ss = v.x * v.x + v.y * v.y + v.z * v.z + v.w * v.w;
#pragma unroll
  for (int off = 32; off > 0; off >>= 1) ss += __shfl_down(ss, off, 64);
  __shared__ float red[4];
  const int w = t >> 6, lane = t & 63;
  if (lane == 0) red[w] = ss;
  __syncthreads();
  const float tot = red[0] + red[1] + red[2] + red[3];
  const float rn = 16.0f / fmaxf(sqrtf(tot), 1e-8f);
  int p = __builtin_amdgcn_cvt_pk_fp8_f32(v.x * rn, v.y * rn, 0, false);
  p = __builtin_amdgcn_cvt_pk_fp8_f32(v.z * rn, v.w * rn, p, true);
  xq[row * 256 + t] = (unsigned int)p;
}

// Fused kernel: MX-FP8 GEMM (128x128 tile, BK=128, 8 kt) over upper-tri
// tiles via mfma_scale_f32_16x16x128_f8f6f4 with unit scales (E8M0 0x7F);
// then the score tile goes to LDS fp16 and both reduce passes (i-side rows,
// j-side cols) stream labels from HBM against the LDS tile.
// LDS is EXACTLY 32768 B -> 5 blocks/CU resident (was 34816 -> 4).
// Staging XOR-swizzle (R2, 0 conflicts): phys 16B group p of row r holds
// logical group p ^ (r&7), applied on the global source address.
// Sim-tile XOR-swizzle (replaces the +8-short pad): 16 groups of 8 fp16 per
// 256B row; phys group = g ^ (row&15). Pass-1 b128 reads 4-way (cheap),
// pass-2 u16 col reads conflict-free, epilogue u16 stores ~4-way (cheap).
__global__ __launch_bounds__(256) void fused_kernel(
    const unsigned char* __restrict__ xq, const float* __restrict__ labels,
    float* __restrict__ accL, float* __restrict__ accS1,
    float* __restrict__ accS2) {
  __shared__ __align__(16) unsigned short S[128 * 128];  // 32768 B
  unsigned char* As8 = (unsigned char*)S;
  unsigned char* Bs8 = As8 + 16384;
  _Float16* st = (_Float16*)S;

  int bi, bj;
  tile_decode(blockIdx.x, bi, bj);
  const bool diag = (bi == bj);
  const int i0 = bi * 128;
  const int j0 = bj * 128;

  const int tid = threadIdx.x;
  const int w = tid >> 6;
  const int lane = tid & 63;
  const int quad = lane >> 4;
  const int l15 = lane & 15;
  const int wr = (w >> 1) * 64;
  const int wc = (w & 1) * 64;

  // staging: 16 chunks of 8 rows x 128B per buffer; each wave does 4 A + 4 B
  const int schunk = w * 4;
  const int srow = lane >> 3;                 // 0..7 row within chunk
  const int scol = ((lane & 7) ^ srow) << 4;  // swizzled 16B src group

  floatx4 acc[4][4];
#pragma unroll
  for (int a = 0; a < 4; ++a)
#pragma unroll
    for (int b = 0; b < 4; ++b) acc[a][b] = (floatx4){0.f, 0.f, 0.f, 0.f};

  for (int kt = 0; kt < 8; ++kt) {
    const int k0 = kt * 128;
#pragma unroll
    for (int it = 0; it < 4; ++it) {
      const int ch = schunk + it;
      load_lds16(xq + (size_t)(i0 + ch * 8 + srow) * DD + k0 + scol,
                 As8 + ch * 1024);
      load_lds16(xq + (size_t)(j0 + ch * 8 + srow) * DD + k0 + scol,
                 Bs8 + ch * 1024);
    }
    __syncthreads();  // drains vmcnt for global_load_lds

    const int m7 = l15 & 7;
    i32x8 bfr[4];
#pragma unroll
    for (int cf = 0; cf < 4; ++cf) {
      const unsigned char* bb = Bs8 + (wc + cf * 16 + l15) * 128;
      const i32x4 lo = *(const i32x4*)(bb + (((2 * quad) ^ m7) << 4));
      const i32x4 hi = *(const i32x4*)(bb + (((2 * quad + 1) ^ m7) << 4));
      bfr[cf] = __builtin_shufflevector(lo, hi, 0, 1, 2, 3, 4, 5, 6, 7);
    }
#pragma unroll
    for (int rf = 0; rf < 4; ++rf) {
      const unsigned char* ab = As8 + (wr + rf * 16 + l15) * 128;
      const i32x4 lo = *(const i32x4*)(ab + (((2 * quad) ^ m7) << 4));
      const i32x4 hi = *(const i32x4*)(ab + (((2 * quad + 1) ^ m7) << 4));
      const i32x8 af = __builtin_shufflevector(lo, hi, 0, 1, 2, 3, 4, 5, 6, 7);
#pragma unroll
      for (int cf = 0; cf < 4; ++cf)
        acc[rf][cf] = __builtin_amdgcn_mfma_scale_f32_16x16x128_f8f6f4(
            af, bfr[cf], acc[rf][cf], 0, 0,  // cbsz/blgp: FP8 e4m3 both
            0, 0x7F7F7F7F,                   // scale A: opsel 0, E8M0 = 1.0
            0, 0x7F7F7F7F);                  // scale B
    }
    __syncthreads();  // also guards the LDS reuse below
  }

  // acc -> LDS sim tile, s = acc * 5/256 (fp8 scale 16*16 + 1/T). C/D
  // layout: col = l15, row = quad*4 + reg (m89/m91, shape-determined).
  // Swizzled store: phys group = (col>>3) ^ (row&15).
#pragma unroll
  for (int rf = 0; rf < 4; ++rf)
#pragma unroll
    for (int cf = 0; cf < 4; ++cf) {
      const int col = wc + cf * 16 + l15;
      const int g = col >> 3;
      const int ce = col & 7;
#pragma unroll
      for (int reg = 0; reg < 4; ++reg) {
        const int row = wr + rf * 16 + quad * 4 + reg;
        st[row * 128 + ((g ^ (row & 15)) << 3) + ce] =
            (_Float16)(acc[rf][cf][reg] * 0.01953125f);
      }
    }
  __syncthreads();

  // ---- pass 1: i-side rows. thread t -> row r = t>>1, col half (t&1)*64.
  {
    const int r = tid >> 1;
    const int ch = (tid & 1) * 64;
    const int gb = ch >> 3;       // logical group base (0 or 8)
    const int rs = r & 15;        // row swizzle key
    float vL = 0.f, v1 = 0.f, v2 = 0.f;
    const float4* lrow =
        (const float4*)(labels + (size_t)(i0 + r) * NN + j0 + ch);
    const _Float16* srow = st + r * 128;
#pragma unroll
    for (int g = 0; g < 8; ++g) {
      const int phys = (gb + g) ^ rs;
      const h16x8 sv = *(const h16x8*)(srow + phys * 8);  // 16B aligned
      const float4 l0 = lrow[2 * g];
      const float4 l1 = lrow[2 * g + 1];
      const float ls[8] = {l0.x, l0.y, l0.z, l0.w, l1.x, l1.y, l1.z, l1.w};
#pragma unroll
      for (int e = 0; e < 8; ++e) {
        const int c = ch + g * 8 + e;
        const float s = (float)sv[e];
        const bool d = diag && (c == r);
        vL += d ? 0.f : __expf(s);
        const float lb = d ? 0.f : ls[e];
        v1 += lb * s;
        v2 += lb;
      }
    }
    vL += __shfl_xor(vL, 1, 64);
    v1 += __shfl_xor(v1, 1, 64);
    v2 += __shfl_xor(v2, 1, 64);
    if (!(tid & 1)) {
      atomicAdd(&accL[i0 + r], vL);
      atomicAdd(&accS1[i0 + r], v1);
      atomicAdd(&accS2[i0 + r], v2);
    }
  }

  // ---- pass 2: j-side cols (off-diag only). thread t -> col c = t&127,
  // row half (t>>7)*64. Labels[j0+c][i0+...] contiguous per thread; sim
  // read col-order from LDS (swizzled u16: 2 lanes/bank, conflict-free).
  if (!diag) {
    const int c = tid & 127;
    const int rb = (tid >> 7) * 64;
    const int cg = c >> 3;
    const int ce = c & 7;
    float vL = 0.f, v1 = 0.f, v2 = 0.f;
    const float4* lrow =
        (const float4*)(labels + (size_t)(j0 + c) * NN + i0 + rb);
#pragma unroll 4
    for (int kk = 0; kk < 16; ++kk) {
      const float4 lb4 = lrow[kk];
      const float ls[4] = {lb4.x, lb4.y, lb4.z, lb4.w};
#pragma unroll
      for (int e = 0; e < 4; ++e) {
        const int rr = rb + kk * 4 + e;
        const float s =
            (float)st[rr * 128 + ((cg ^ (rr & 15)) << 3) + ce];
        vL += __expf(s);
        v1 += ls[e] * s;
        v2 += ls[e];
      }
    }
    atomicAdd(&accL[j0 + c], vL);
    atomicAdd(&accS1[j0 + c], v1);
    atomicAdd(&accS2[j0 + c], v2);
  }
}

// Kernel 3: loss = mean_i( S2_i*log(l_i) - S1_i )
__global__ __launch_bounds__(256) void finalize_kernel(
    const float* __restrict__ accL, const float* __restrict__ accS1,
    const float* __restrict__ accS2, float* __restrict__ out) {
  const int t = threadIdx.x;
  float sum = 0.f;
  for (int i = t; i < NN; i += 256)
    sum += accS2[i] * logf(accL[i]) - accS1[i];
#pragma unroll
  for (int off = 32; off > 0; off >>= 1) sum += __shfl_down(sum, off, 64);
  __shared__ float red[4];
  const int w = t >> 6, lane = t & 63;
  if (lane == 0) red[w] = sum;
  __syncthreads();
  if (t == 0) out[0] = (red[0] + red[1] + red[2] + red[3]) / (float)NN;
}

extern "C" void kernel_launch(void* const* d_in, const int* in_sizes, int n_in,
                              void* d_out, int out_size, void* d_ws,
                              size_t ws_size, hipStream_t stream) {
  const float* embs = (const float*)d_in[0];    // (8192,1024) fp32
  const float* labels = (const float*)d_in[1];  // (8192,8192) fp32
  float* out = (float*)d_out;

  // workspace: [0,8MB) fp8 normalized X (x16); then 3 x 8192 fp32 accums
  unsigned int* xq = (unsigned int*)d_ws;
  float* accL = (float*)((char*)d_ws + (size_t)NN * DD);
  float* accS1 = accL + NN;
  float* accS2 = accS1 + NN;

  normalize_kernel<<<NN, 256, 0, stream>>>(embs, xq, accL, accS1, accS2);
  fused_kernel<<<NUT, 256, 0, stream>>>((const unsigned char*)xq, labels,
                                        accL, accS1, accS2);
  finalize_kernel<<<1, 256, 0, stream>>>(accL, accS1, accS2, out);
}